// Round 1
// baseline (568.215 us; speedup 1.0000x reference)
//
#include <hip/hip_runtime.h>

typedef __bf16 bf16;
typedef bf16 bf16x8 __attribute__((ext_vector_type(8)));
typedef float floatx4 __attribute__((ext_vector_type(4)));

__device__ __forceinline__ float mish_f(float x) {
  // mish(x) = x * tanh(softplus(x)) = x * (p^2-1)/(p^2+1), p = 1+e^x
  float e = __expf(fminf(x, 20.0f));
  float p = 1.0f + e;
  float p2 = p * p;
  return x * (p2 - 1.0f) * __builtin_amdgcn_rcpf(p2 + 1.0f);
}

// ------------------------------------------------------------------
// Prep: fp32 -> bf16 for embeddings (row-major) and the 8 weight
// matrices (MFMA B-fragment order).
// B-frag layout for mfma_f32_16x16x32_bf16:
//   Wp[((kt*(D/16)+ct)*64 + lane)*8 + j] = W[kt*32 + (lane>>4)*8 + j][ct*16 + (lane&15)]
// ------------------------------------------------------------------
struct PrepArgs {
  const float* emb;
  const float* W[8];   // W1_p0, W2_p0, W1_p1, W2_p1, W1_p2, W2_p2, W1_p3, W2_p3
  bf16* emb_bf;
  bf16* Wp[8];
};

__global__ __launch_bounds__(256) void prep_kernel(PrepArgs a) {
  const int idx = blockIdx.x * 256 + threadIdx.x;
  const int EMB_N = 2048 * 128;
  if (idx < EMB_N) {
    a.emb_bf[idx] = (bf16)a.emb[idx];
    return;
  }
  int t = idx - EMB_N;
  int m, local, D, lognct;
  if (t < 32768) {            // p0: two 128x128 matrices
    m = t >> 14; local = t & 16383; D = 128; lognct = 3;
  } else {                    // p1..p3: six 256x256 matrices
    int u = t - 32768;
    m = 2 + (u >> 16); local = u & 65535; D = 256; lognct = 4;
  }
  if (m >= 8) return;
  const int j    = local & 7;
  const int lane = (local >> 3) & 63;
  const int ctk  = local >> 9;
  const int ct   = ctk & ((1 << lognct) - 1);
  const int kt   = ctk >> lognct;
  const int row  = kt * 32 + (lane >> 4) * 8 + j;
  const int col  = ct * 16 + (lane & 15);
  a.Wp[m][local] = (bf16)a.W[m][row * D + col];
}

// ------------------------------------------------------------------
// Shared GEMM inner loop: 64 rows (4 m-tiles) x (CPW*16) cols per wave,
// K = NKT*32, A from LDS (row stride STRIDE bf16), B from fragment-order
// global memory.
// ------------------------------------------------------------------
template <int NCT, int NKT, int STRIDE, int CPW>
__device__ __forceinline__ void gemm_tiles(const bf16* lds_a,
                                           const bf16* __restrict__ Wp,
                                           int w, int lane,
                                           floatx4 acc[4][CPW]) {
  const int l15 = lane & 15;
  const int q   = lane >> 4;
  for (int kt = 0; kt < NKT; ++kt) {
    bf16x8 af[4];
#pragma unroll
    for (int mt = 0; mt < 4; ++mt)
      af[mt] = *(const bf16x8*)&lds_a[(mt * 16 + l15) * STRIDE + kt * 32 + q * 8];
    bf16x8 bfr[CPW];
#pragma unroll
    for (int c = 0; c < CPW; ++c)
      bfr[c] = *(const bf16x8*)(Wp + (((kt * NCT) + (w * CPW + c)) * 64 + lane) * 8);
#pragma unroll
    for (int mt = 0; mt < 4; ++mt)
#pragma unroll
      for (int c = 0; c < CPW; ++c)
        acc[mt][c] = __builtin_amdgcn_mfma_f32_16x16x32_bf16(af[mt], bfr[c], acc[mt][c], 0, 0, 0);
  }
}

// ------------------------------------------------------------------
// Arity-2 fused residual MLP (D = 256). One WG = 64 consecutive pair
// rows (fixed b,i; j = 0..63) x 256 cols. blockIdx.y = predicate.
// ------------------------------------------------------------------
struct A2Args {
  const bf16* emb_bf;
  const float* emb_f;
  const bf16* W1p[3];
  const float* b1[3];
  const bf16* W2p[3];
  const float* b2[3];
  float* out[3];
};

__global__ __launch_bounds__(256, 4) void fused_a2(A2Args a) {
  const int p  = blockIdx.y;
  const int r0 = blockIdx.x * 64;
  const int bb = r0 >> 12;          // batch index
  const int ii = (r0 >> 6) & 63;    // left object index (fixed per WG)
  const int t  = threadIdx.x;
  const int lane = t & 63;
  const int w    = t >> 6;
  const int l15  = lane & 15;
  const int q    = lane >> 4;

  __shared__ bf16 lds[64 * 264];    // rows for GEMM1, then H for GEMM2

  // ---- Phase 1: stage pair-rows (bf16) into LDS
  {
    const int row = t >> 2;
    const int qt  = t & 3;
    const bf16* src = (qt < 2)
        ? (a.emb_bf + (bb * 64 + ii) * 128 + qt * 64)          // left half: broadcast
        : (a.emb_bf + (bb * 64 + row) * 128 + (qt - 2) * 64);  // right half: row j
    const uint4* s4 = (const uint4*)src;
    uint4* d4 = (uint4*)&lds[row * 264 + qt * 64];
#pragma unroll
    for (int u = 0; u < 8; ++u) d4[u] = s4[u];
  }
  __syncthreads();

  // ---- GEMM1: rows @ W1
  floatx4 acc[4][4];
#pragma unroll
  for (int mt = 0; mt < 4; ++mt)
#pragma unroll
    for (int c = 0; c < 4; ++c) acc[mt][c] = (floatx4){0.f, 0.f, 0.f, 0.f};
  gemm_tiles<16, 8, 264, 4>(lds, a.W1p[p], w, lane, acc);

  float b1v[4];
  {
    const float* b1 = a.b1[p];
#pragma unroll
    for (int c = 0; c < 4; ++c) b1v[c] = b1[w * 64 + c * 16 + l15];
  }

  __syncthreads();  // all waves done reading rows
  // ---- mish + write H (bf16) over the same LDS buffer
#pragma unroll
  for (int mt = 0; mt < 4; ++mt)
#pragma unroll
    for (int c = 0; c < 4; ++c) {
      const int col = w * 64 + c * 16 + l15;
#pragma unroll
      for (int r = 0; r < 4; ++r) {
        float x = acc[mt][c][r] + b1v[c];
        lds[(mt * 16 + q * 4 + r) * 264 + col] = (bf16)mish_f(x);
      }
    }
  __syncthreads();

  // ---- GEMM2: H @ W2
#pragma unroll
  for (int mt = 0; mt < 4; ++mt)
#pragma unroll
    for (int c = 0; c < 4; ++c) acc[mt][c] = (floatx4){0.f, 0.f, 0.f, 0.f};
  gemm_tiles<16, 8, 264, 4>(lds, a.W2p[p], w, lane, acc);

  // ---- Epilogue: + b2 + fp32 residual, store
  float b2v[4];
  {
    const float* b2 = a.b2[p];
#pragma unroll
    for (int c = 0; c < 4; ++c) b2v[c] = b2[w * 64 + c * 16 + l15];
  }
  const float* embL = a.emb_f + (bb * 64 + ii) * 128;
  const float* embR = a.emb_f + (bb * 64) * 128;
  float* outp = a.out[p] + (size_t)r0 * 256;

  if (w < 2) {  // cols 0..127: left residual, same for every row in tile
    float resv[4];
#pragma unroll
    for (int c = 0; c < 4; ++c) resv[c] = embL[w * 64 + c * 16 + l15];
#pragma unroll
    for (int mt = 0; mt < 4; ++mt)
#pragma unroll
      for (int c = 0; c < 4; ++c) {
        const int col = w * 64 + c * 16 + l15;
#pragma unroll
        for (int r = 0; r < 4; ++r) {
          const int rl = mt * 16 + q * 4 + r;
          outp[rl * 256 + col] = acc[mt][c][r] + b2v[c] + resv[c];
        }
      }
  } else {      // cols 128..255: right residual depends on row (j = rl)
#pragma unroll
    for (int mt = 0; mt < 4; ++mt)
#pragma unroll
      for (int c = 0; c < 4; ++c) {
        const int col = w * 64 + c * 16 + l15;
#pragma unroll
        for (int r = 0; r < 4; ++r) {
          const int rl = mt * 16 + q * 4 + r;
          outp[rl * 256 + col] = acc[mt][c][r] + b2v[c] + embR[rl * 128 + (col - 128)];
        }
      }
  }
}

// ------------------------------------------------------------------
// Arity-1 fused residual MLP (D = 128), p0. 32 WGs of 64 rows.
// ------------------------------------------------------------------
struct A1Args {
  const bf16* emb_bf;
  const float* emb_f;
  const bf16* W1p;
  const float* b1;
  const bf16* W2p;
  const float* b2;
  float* out;
};

__global__ __launch_bounds__(256, 4) void fused_a1(A1Args a) {
  const int r0 = blockIdx.x * 64;
  const int t  = threadIdx.x;
  const int lane = t & 63;
  const int w    = t >> 6;
  const int l15  = lane & 15;
  const int q    = lane >> 4;

  __shared__ bf16 lds[64 * 136];

  {
    const int row = t >> 2;
    const int qt  = t & 3;
    const bf16* src = a.emb_bf + (r0 + row) * 128 + qt * 32;
    const uint4* s4 = (const uint4*)src;
    uint4* d4 = (uint4*)&lds[row * 136 + qt * 32];
#pragma unroll
    for (int u = 0; u < 4; ++u) d4[u] = s4[u];
  }
  __syncthreads();

  floatx4 acc[4][2];
#pragma unroll
  for (int mt = 0; mt < 4; ++mt)
#pragma unroll
    for (int c = 0; c < 2; ++c) acc[mt][c] = (floatx4){0.f, 0.f, 0.f, 0.f};
  gemm_tiles<8, 4, 136, 2>(lds, a.W1p, w, lane, acc);

  float b1v[2];
#pragma unroll
  for (int c = 0; c < 2; ++c) b1v[c] = a.b1[w * 32 + c * 16 + l15];

  __syncthreads();
#pragma unroll
  for (int mt = 0; mt < 4; ++mt)
#pragma unroll
    for (int c = 0; c < 2; ++c) {
      const int col = w * 32 + c * 16 + l15;
#pragma unroll
      for (int r = 0; r < 4; ++r) {
        float x = acc[mt][c][r] + b1v[c];
        lds[(mt * 16 + q * 4 + r) * 136 + col] = (bf16)mish_f(x);
      }
    }
  __syncthreads();

#pragma unroll
  for (int mt = 0; mt < 4; ++mt)
#pragma unroll
    for (int c = 0; c < 2; ++c) acc[mt][c] = (floatx4){0.f, 0.f, 0.f, 0.f};
  gemm_tiles<8, 4, 136, 2>(lds, a.W2p, w, lane, acc);

  float b2v[2];
#pragma unroll
  for (int c = 0; c < 2; ++c) b2v[c] = a.b2[w * 32 + c * 16 + l15];

#pragma unroll
  for (int mt = 0; mt < 4; ++mt)
#pragma unroll
    for (int c = 0; c < 2; ++c) {
      const int col = w * 32 + c * 16 + l15;
#pragma unroll
      for (int r = 0; r < 4; ++r) {
        const int rl = mt * 16 + q * 4 + r;
        a.out[(r0 + rl) * 128 + col] =
            acc[mt][c][r] + b2v[c] + a.emb_f[(r0 + rl) * 128 + col];
      }
    }
}

// ------------------------------------------------------------------
extern "C" void kernel_launch(void* const* d_in, const int* in_sizes, int n_in,
                              void* d_out, int out_size, void* d_ws, size_t ws_size,
                              hipStream_t stream) {
  const float* emb_f = (const float*)d_in[0];
  // d_in: 0 emb, 1 num_objects, then W1,b1,W2,b2 per predicate p0..p3
  const float* W1s[4], *b1s[4], *W2s[4], *b2s[4];
  for (int p = 0; p < 4; ++p) {
    W1s[p] = (const float*)d_in[2 + p * 4 + 0];
    b1s[p] = (const float*)d_in[2 + p * 4 + 1];
    W2s[p] = (const float*)d_in[2 + p * 4 + 2];
    b2s[p] = (const float*)d_in[2 + p * 4 + 3];
  }

  char* ws = (char*)d_ws;
  bf16* emb_bf = (bf16*)ws;
  size_t off = (size_t)2048 * 128 * 2;  // 524288
  bf16* Wp[8];
  const size_t wbytes[8] = {32768, 32768, 131072, 131072, 131072, 131072, 131072, 131072};
  for (int m = 0; m < 8; ++m) { Wp[m] = (bf16*)(ws + off); off += wbytes[m]; }

  PrepArgs pa;
  pa.emb = emb_f;
  pa.emb_bf = emb_bf;
  const float* Wsrc[8] = {W1s[0], W2s[0], W1s[1], W2s[1], W1s[2], W2s[2], W1s[3], W2s[3]};
  for (int m = 0; m < 8; ++m) { pa.W[m] = Wsrc[m]; pa.Wp[m] = Wp[m]; }
  // total elements: 262144 (emb) + 425984 (weights) = 688128 = 2688 * 256
  prep_kernel<<<2688, 256, 0, stream>>>(pa);

  float* out = (float*)d_out;

  A1Args a1;
  a1.emb_bf = emb_bf; a1.emb_f = emb_f;
  a1.W1p = Wp[0]; a1.b1 = b1s[0]; a1.W2p = Wp[1]; a1.b2 = b2s[0];
  a1.out = out;
  fused_a1<<<32, 256, 0, stream>>>(a1);

  A2Args a2;
  a2.emb_bf = emb_bf; a2.emb_f = emb_f;
  size_t o = 2048 * 128;  // after p0 output
  for (int p = 0; p < 3; ++p) {
    a2.W1p[p] = Wp[2 + p * 2];
    a2.W2p[p] = Wp[3 + p * 2];
    a2.b1[p] = b1s[p + 1];
    a2.b2[p] = b2s[p + 1];
    a2.out[p] = out + o + (size_t)p * 131072 * 256;
  }
  fused_a2<<<dim3(2048, 3), 256, 0, stream>>>(a2);
}